// Round 9
// baseline (62.441 us; speedup 1.0000x reference)
//
#include <hip/hip_runtime.h>

constexpr int DSZ = 192, HSZ = 192, WSZ = 192, BSZ = 2;
constexpr int WQ = WSZ / 4;                  // 48 float4 per row
constexpr int DT = 6;                        // planes marched per thread
constexpr int CHUNKS = DSZ / DT;             // 32 d-chunks
constexpr int TPB = 256;
constexpr int NCOL = BSZ * HSZ * WQ;         // 18432 (b,h,wq) columns
constexpr int NBLOCKS = NCOL * CHUNKS / TPB; // 2304, %8==0, 9 blocks/CU
constexpr int HW = HSZ * WSZ;
constexpr float SMOOTH = 1e-5f;

__device__ __forceinline__ float4 ld4(const float* __restrict__ p) {
    return *reinterpret_cast<const float4*>(p);
}

__device__ __forceinline__ float fsqrt(float x) {
    return __builtin_amdgcn_sqrtf(x);   // raw v_sqrt_f32
}

// 4-wide boundary magnitude
__device__ __forceinline__ void mag4(float4 c, float4 hm, float4 hn,
                                     float4 d0, float4 d1, float wl, float wr,
                                     float o[4]) {
    float gx0 = d1.x - d0.x, gx1 = d1.y - d0.y, gx2 = d1.z - d0.z, gx3 = d1.w - d0.w;
    float gy0 = hn.x - hm.x, gy1 = hn.y - hm.y, gy2 = hn.z - hm.z, gy3 = hn.w - hm.w;
    float gz0 = c.y - wl,    gz1 = c.z - c.x,   gz2 = c.w - c.y,   gz3 = wr - c.z;
    o[0] = fsqrt(fmaf(gx0, gx0, fmaf(gy0, gy0, fmaf(gz0, gz0, SMOOTH))));
    o[1] = fsqrt(fmaf(gx1, gx1, fmaf(gy1, gy1, fmaf(gz1, gz1, SMOOTH))));
    o[2] = fsqrt(fmaf(gx2, gx2, fmaf(gy2, gy2, fmaf(gz2, gz2, SMOOTH))));
    o[3] = fsqrt(fmaf(gx3, gx3, fmaf(gy3, gy3, fmaf(gz3, gz3, SMOOTH))));
}

// w-edges via cross-lane shuffle: lane l-1 owns X[-1] (its .w), lane l+1 owns X[4] (its .x)
__device__ __forceinline__ void edges(float4 r, int wq, float& wl, float& wr) {
    float up = __shfl_up(r.w, 1);
    float dn = __shfl_down(r.x, 1);
    wl = (wq > 0)      ? up : 0.f;
    wr = (wq < WQ - 1) ? dn : 0.f;
}

__global__ __launch_bounds__(TPB)
void bl_main(const float* __restrict__ pred,
             const float* __restrict__ target,
             double* __restrict__ acc) {
    // XCD-chunked swizzle: each XCD gets a contiguous slab of blocks
    const int swz = (blockIdx.x & 7) * (NBLOCKS / 8) + (blockIdx.x >> 3);
    const int pid = swz * TPB + threadIdx.x;

    const int wq = pid % WQ;
    int t        = pid / WQ;
    const int h  = t % HSZ;
    t            = t / HSZ;
    const int dc = t % CHUNKS;
    const int b  = t / CHUNKS;
    const int d0 = dc * DT;

    const float4 z = make_float4(0.f, 0.f, 0.f, 0.f);
    const float* __restrict__ P = pred   + (size_t)b * DSZ * HW + (size_t)h * WSZ + wq * 4;
    const float* __restrict__ T = target + (size_t)b * DSZ * HW + (size_t)h * WSZ + wq * 4;

    // rolling 2-plane window (single row per plane)
    float4 pm, pc, tm, tc;
    pc = ld4(P + (size_t)d0 * HW);
    tc = ld4(T + (size_t)d0 * HW);
    if (d0 > 0) {
        pm = ld4(P + (size_t)(d0 - 1) * HW);
        tm = ld4(T + (size_t)(d0 - 1) * HW);
    } else {
        pm = z; tm = z;
    }

    float s_pt = 0.f, s_p = 0.f, s_t = 0.f;

    #pragma unroll 1
    for (int s = 0; s < DT; ++s) {
        const int d = d0 + s;
        const size_t dOff = (size_t)d * HW;

        float4 pp  = (d < DSZ - 1) ? ld4(P + dOff + HW)  : z;
        float4 tp  = (d < DSZ - 1) ? ld4(T + dOff + HW)  : z;
        float4 phm = (h > 0)       ? ld4(P + dOff - WSZ) : z;
        float4 thm = (h > 0)       ? ld4(T + dOff - WSZ) : z;
        float4 phn = (h < HSZ - 1) ? ld4(P + dOff + WSZ) : z;
        float4 thn = (h < HSZ - 1) ? ld4(T + dOff + WSZ) : z;

        float wl, wr;
        float pb[4], tb[4];
        edges(pc, wq, wl, wr);
        mag4(pc, phm, phn, pm, pp, wl, wr, pb);
        edges(tc, wq, wl, wr);
        mag4(tc, thm, thn, tm, tp, wl, wr, tb);

        #pragma unroll
        for (int j = 0; j < 4; ++j) {
            s_pt = fmaf(pb[j], tb[j], s_pt);
            s_p += pb[j];
            s_t += tb[j];
        }

        pm = pc; pc = pp;
        tm = tc; tc = tp;
    }

    // 64-lane wave reduction
    #pragma unroll
    for (int off = 32; off; off >>= 1) {
        s_pt += __shfl_down(s_pt, off);
        s_p  += __shfl_down(s_p,  off);
        s_t  += __shfl_down(s_t,  off);
    }

    __shared__ float red[4][4];   // 4 waves x {pt,p,t}
    const int lane = threadIdx.x & 63;
    const int wid  = threadIdx.x >> 6;
    if (lane == 0) {
        red[wid][0] = s_pt;
        red[wid][1] = s_p;
        red[wid][2] = s_t;
    }
    __syncthreads();
    if (threadIdx.x == 0) {
        double a_pt = 0.0, a_p = 0.0, a_t = 0.0;
        #pragma unroll
        for (int k = 0; k < 4; ++k) {
            a_pt += (double)red[k][0];
            a_p  += (double)red[k][1];
            a_t  += (double)red[k][2];
        }
        atomicAdd(&acc[0],  a_pt);
        atomicAdd(&acc[8],  a_p);
        atomicAdd(&acc[16], a_t);
    }
}

__global__ void bl_final(const double* __restrict__ acc, float* __restrict__ out) {
    const double I = acc[0];
    const double Pm = acc[8];
    const double Tm = acc[16];
    const double dice = (2.0 * I + 1e-5) / (Pm + Tm + 1e-5);
    out[0] = (float)(1.0 - dice);
}

extern "C" void kernel_launch(void* const* d_in, const int* in_sizes, int n_in,
                              void* d_out, int out_size, void* d_ws, size_t ws_size,
                              hipStream_t stream) {
    const float* pred   = (const float*)d_in[0];
    const float* target = (const float*)d_in[1];
    double* acc = (double*)d_ws;

    (void)hipMemsetAsync(d_ws, 0, 17 * sizeof(double), stream);
    bl_main<<<NBLOCKS, TPB, 0, stream>>>(pred, target, acc);
    bl_final<<<1, 1, 0, stream>>>(acc, (float*)d_out);
}

// Round 10
// 36.942 us; speedup vs baseline: 1.6903x; 1.6903x over previous
//
#include <hip/hip_runtime.h>

constexpr int DSZ = 192, HSZ = 192, WSZ = 192, BSZ = 2;
constexpr int WQ  = WSZ / 4;            // 48 float4 per row
constexpr int HT  = 12;                 // h-rows per tile
constexpr int NHT = HSZ / HT;           // 16
constexpr int DT  = 12;                 // planes per d-chunk
constexpr int NDC = DSZ / DT;           // 16
constexpr int TPB = 192;
constexpr int NBLOCKS = BSZ * NHT * NDC;   // 512 = 2 blocks/CU, %8==0
constexpr int PPT = HT * WQ / TPB;      // 3 positions per thread
constexpr int HW  = HSZ * WSZ;
constexpr float SMOOTH = 1e-5f;

__device__ __forceinline__ float4 ld4(const float* __restrict__ p) {
    return *reinterpret_cast<const float4*>(p);
}

__device__ __forceinline__ float fsqrt(float x) {
    return __builtin_amdgcn_sqrtf(x);
}

__device__ __forceinline__ void mag4(float4 c, float4 hm, float4 hn,
                                     float4 d0, float4 d1, float wl, float wr,
                                     float o[4]) {
    float gx0 = d1.x - d0.x, gx1 = d1.y - d0.y, gx2 = d1.z - d0.z, gx3 = d1.w - d0.w;
    float gy0 = hn.x - hm.x, gy1 = hn.y - hm.y, gy2 = hn.z - hm.z, gy3 = hn.w - hm.w;
    float gz0 = c.y - wl,    gz1 = c.z - c.x,   gz2 = c.w - c.y,   gz3 = wr - c.z;
    o[0] = fsqrt(fmaf(gx0, gx0, fmaf(gy0, gy0, fmaf(gz0, gz0, SMOOTH))));
    o[1] = fsqrt(fmaf(gx1, gx1, fmaf(gy1, gy1, fmaf(gz1, gz1, SMOOTH))));
    o[2] = fsqrt(fmaf(gx2, gx2, fmaf(gy2, gy2, fmaf(gz2, gz2, SMOOTH))));
    o[3] = fsqrt(fmaf(gx3, gx3, fmaf(gy3, gy3, fmaf(gz3, gz3, SMOOTH))));
}

// w-edges via cross-lane shuffle (wrap lanes are exactly the masked ones)
__device__ __forceinline__ void edges(float4 r, int wq, float& wl, float& wr) {
    float up = __shfl_up(r.w, 1);
    float dn = __shfl_down(r.x, 1);
    wl = (wq > 0)      ? up : 0.f;
    wr = (wq < WQ - 1) ? dn : 0.f;
}

__global__ __launch_bounds__(TPB)
void bl_main(const float* __restrict__ pred,
             const float* __restrict__ target,
             double* __restrict__ acc) {
    // LDS: 2 buffers x 2 arrays x (HT+2) rows x 48 float4 = 43 KB
    __shared__ float4 sbuf[2][2][HT + 2][WQ];

    const int bid = (int)blockIdx.x;
    const int swz = (bid & 7) * (NBLOCKS / 8) + (bid >> 3);  // XCD-chunked
    int t = swz;
    const int dc = t % NDC; t /= NDC;
    const int ht = t % NHT; t /= NHT;
    const int b  = t;
    const int d0 = dc * DT;
    const int h0 = ht * HT;

    const int tid = threadIdx.x;
    const int wq  = tid % WQ;
    const int r0  = tid / WQ;          // 0..3; rows handled: r0+4k

    const float4 z = make_float4(0.f, 0.f, 0.f, 0.f);
    const float* __restrict__ base0 = pred   + (size_t)b * DSZ * HW + (size_t)h0 * WSZ + wq * 4;
    const float* __restrict__ base1 = target + (size_t)b * DSZ * HW + (size_t)h0 * WSZ + wq * 4;
    const float* base[2] = { base0, base1 };

    // halo roles: threads 0..47 -> row -1, threads 48..95 -> row HT
    const bool isHalo = (tid < 2 * WQ);
    const int  hrow   = (tid < WQ) ? -1 : HT;
    const int  hwq    = (tid < WQ) ? tid : tid - WQ;
    const bool hvalid = isHalo && (h0 + hrow >= 0) && (h0 + hrow < HSZ);
    const float* hbase[2] = {
        pred   + (size_t)b * DSZ * HW + (size_t)(h0 + hrow) * WSZ + hwq * 4,
        target + (size_t)b * DSZ * HW + (size_t)(h0 + hrow) * WSZ + hwq * 4 };

    float4 cP[PPT][2], cC[PPT][2], cN[PPT][2], gN[PPT][2];
    float4 hNxt[2], gH[2];

    // ---- prologue: own rows at planes d0-1, d0, d0+1; halos at d0, d0+1
    #pragma unroll
    for (int k = 0; k < PPT; ++k) {
        const size_t ro = (size_t)(r0 + 4 * k) * WSZ;
        #pragma unroll
        for (int a = 0; a < 2; ++a) {
            cP[k][a] = (d0 > 0) ? ld4(base[a] + ro + (size_t)(d0 - 1) * HW) : z;
            cC[k][a] = ld4(base[a] + ro + (size_t)d0 * HW);
            cN[k][a] = ld4(base[a] + ro + (size_t)(d0 + 1) * HW);   // d0+1 <= 181 always
        }
    }
    float4 hCur[2];
    #pragma unroll
    for (int a = 0; a < 2; ++a) {
        hCur[a] = hvalid ? ld4(hbase[a] + (size_t)d0 * HW)       : z;
        hNxt[a] = hvalid ? ld4(hbase[a] + (size_t)(d0 + 1) * HW) : z;
    }
    // stage plane d0 into buffer 0
    #pragma unroll
    for (int k = 0; k < PPT; ++k)
        #pragma unroll
        for (int a = 0; a < 2; ++a)
            sbuf[0][a][r0 + 4 * k + 1][wq] = cC[k][a];
    if (isHalo) {
        #pragma unroll
        for (int a = 0; a < 2; ++a)
            sbuf[0][a][hrow + 1][hwq] = hCur[a];
    }
    __syncthreads();

    float s_pt = 0.f, s_p = 0.f, s_t = 0.f;

    // ---- main d-march: compute plane d0+s, prefetch d0+s+2, stage d0+s+1
    #pragma unroll 1
    for (int s = 0; s < DT; ++s) {
        const int cur = s & 1, nxt = cur ^ 1;
        const int q = d0 + s + 2;
        const bool vq = (q < DSZ);

        // 1. issue prefetch of plane q (consumed only after compute)
        #pragma unroll
        for (int k = 0; k < PPT; ++k) {
            const size_t ro = (size_t)(r0 + 4 * k) * WSZ + (size_t)q * HW;
            #pragma unroll
            for (int a = 0; a < 2; ++a)
                gN[k][a] = vq ? ld4(base[a] + ro) : z;
        }
        #pragma unroll
        for (int a = 0; a < 2; ++a)
            gH[a] = (vq && hvalid) ? ld4(hbase[a] + (size_t)q * HW) : z;

        // 2. compute plane d0+s (h-halo from LDS, d-window regs, w via shuffle)
        #pragma unroll
        for (int k = 0; k < PPT; ++k) {
            const int r = r0 + 4 * k;
            float m[2][4];
            #pragma unroll
            for (int a = 0; a < 2; ++a) {
                float4 hm = sbuf[cur][a][r][wq];       // logical row r-1
                float4 hn = sbuf[cur][a][r + 2][wq];   // logical row r+1
                float wl, wr;
                edges(cC[k][a], wq, wl, wr);
                mag4(cC[k][a], hm, hn, cP[k][a], cN[k][a], wl, wr, m[a]);
            }
            #pragma unroll
            for (int j = 0; j < 4; ++j) {
                s_pt = fmaf(m[0][j], m[1][j], s_pt);
                s_p += m[0][j];
                s_t += m[1][j];
            }
        }

        // 3. stage plane d0+s+1 into nxt (waitcnt for gN folds in here, after compute)
        #pragma unroll
        for (int k = 0; k < PPT; ++k)
            #pragma unroll
            for (int a = 0; a < 2; ++a)
                sbuf[nxt][a][r0 + 4 * k + 1][wq] = cN[k][a];
        if (isHalo) {
            #pragma unroll
            for (int a = 0; a < 2; ++a)
                sbuf[nxt][a][hrow + 1][hwq] = hNxt[a];
        }

        // 4. roll windows
        #pragma unroll
        for (int k = 0; k < PPT; ++k)
            #pragma unroll
            for (int a = 0; a < 2; ++a) {
                cP[k][a] = cC[k][a];
                cC[k][a] = cN[k][a];
                cN[k][a] = gN[k][a];
            }
        hNxt[0] = gH[0]; hNxt[1] = gH[1];
        __syncthreads();
    }

    // ---- reduction (3 waves)
    #pragma unroll
    for (int off = 32; off; off >>= 1) {
        s_pt += __shfl_down(s_pt, off);
        s_p  += __shfl_down(s_p,  off);
        s_t  += __shfl_down(s_t,  off);
    }

    __shared__ float red[3][4];
    const int lane = tid & 63;
    const int wid  = tid >> 6;
    if (lane == 0) {
        red[wid][0] = s_pt;
        red[wid][1] = s_p;
        red[wid][2] = s_t;
    }
    __syncthreads();
    if (tid == 0) {
        double a_pt = 0.0, a_p = 0.0, a_t = 0.0;
        #pragma unroll
        for (int k = 0; k < 3; ++k) {
            a_pt += (double)red[k][0];
            a_p  += (double)red[k][1];
            a_t  += (double)red[k][2];
        }
        atomicAdd(&acc[0],  a_pt);
        atomicAdd(&acc[8],  a_p);
        atomicAdd(&acc[16], a_t);
    }
}

__global__ void bl_final(const double* __restrict__ acc, float* __restrict__ out) {
    const double I = acc[0];
    const double Pm = acc[8];
    const double Tm = acc[16];
    const double dice = (2.0 * I + 1e-5) / (Pm + Tm + 1e-5);
    out[0] = (float)(1.0 - dice);
}

extern "C" void kernel_launch(void* const* d_in, const int* in_sizes, int n_in,
                              void* d_out, int out_size, void* d_ws, size_t ws_size,
                              hipStream_t stream) {
    const float* pred   = (const float*)d_in[0];
    const float* target = (const float*)d_in[1];
    double* acc = (double*)d_ws;

    (void)hipMemsetAsync(d_ws, 0, 17 * sizeof(double), stream);
    bl_main<<<NBLOCKS, TPB, 0, stream>>>(pred, target, acc);
    bl_final<<<1, 1, 0, stream>>>(acc, (float*)d_out);
}